// Round 1
// baseline (27.648 us; speedup 1.0000x reference)
//
#include <hip/hip_runtime.h>
#include <math.h>

// CustomCombinedLoss: BCE(sum, weighted) over positive_prob + MultiMarginLoss(p=1, margin=0.5)
// B=16384 rows, C=2048 classes. Memory-bound on predictions (134 MB f32).

#define BN   16384
#define CN   2048
#define NBLK 1024
#define NTHR 256

__global__ __launch_bounds__(NTHR) void loss_partial_kernel(
    const float* __restrict__ pp,     // [B] positive_prob
    const float* __restrict__ pred,   // [B*C] predictions
    const int*   __restrict__ tgt,    // [B] target in [0, C]
    float* __restrict__ partial)      // [NBLK] per-block partial sums
{
    const int tid = threadIdx.x;
    float acc_h = 0.f;   // hinge terms (scaled by 1/C at the end)
    float acc_o = 0.f;   // BCE terms

    for (int row = blockIdx.x; row < BN; row += NBLK) {
        const int t = tgt[row];

        if (tid == 0) {
            const float p = pp[row];
            if (t != 0) {
                // positive: w=1, -max(log p, -100)
                acc_o -= fmaxf(logf(p), -100.f);
            } else {
                // negative: w=2, -2*max(log1p(-p), -100)
                acc_o -= 2.0f * fmaxf(log1pf(-p), -100.f);
            }
        }
        if (t == 0) continue;   // no margin term for negative samples

        const int y = t - 1;
        const float* rowp = pred + (size_t)row * CN;
        const float xy = rowp[y];            // uniform address -> single broadcast txn
        const float c  = 0.5f - xy;          // margin - x[y]

        // 2048 floats = 512 float4; 256 threads -> 2 float4 each, coalesced
        const float4* rp4 = (const float4*)rowp;
        const float4 a = rp4[tid];
        const float4 b = rp4[tid + NTHR];
        acc_h += fmaxf(0.f, c + a.x) + fmaxf(0.f, c + a.y)
               + fmaxf(0.f, c + a.z) + fmaxf(0.f, c + a.w)
               + fmaxf(0.f, c + b.x) + fmaxf(0.f, c + b.y)
               + fmaxf(0.f, c + b.z) + fmaxf(0.f, c + b.w);
        if (tid == 0) acc_h -= 0.5f;         // remove the j==y term: max(0, margin) = 0.5
    }

    float acc = acc_h * (1.0f / CN) + acc_o;

    // deterministic block reduce: wave64 shuffle tree, then LDS across 4 waves
    #pragma unroll
    for (int off = 32; off > 0; off >>= 1)
        acc += __shfl_down(acc, off, 64);
    __shared__ float sm[NTHR / 64];
    if ((tid & 63) == 0) sm[tid >> 6] = acc;
    __syncthreads();
    if (tid == 0) {
        float s = 0.f;
        #pragma unroll
        for (int i = 0; i < NTHR / 64; ++i) s += sm[i];
        partial[blockIdx.x] = s;
    }
}

__global__ __launch_bounds__(NTHR) void loss_final_kernel(
    const float* __restrict__ partial, float* __restrict__ out)
{
    const int tid = threadIdx.x;
    float acc = 0.f;
    for (int i = tid; i < NBLK; i += NTHR) acc += partial[i];
    #pragma unroll
    for (int off = 32; off > 0; off >>= 1)
        acc += __shfl_down(acc, off, 64);
    __shared__ float sm[NTHR / 64];
    if ((tid & 63) == 0) sm[tid >> 6] = acc;
    __syncthreads();
    if (tid == 0) {
        float s = 0.f;
        #pragma unroll
        for (int i = 0; i < NTHR / 64; ++i) s += sm[i];
        out[0] = s;
    }
}

extern "C" void kernel_launch(void* const* d_in, const int* in_sizes, int n_in,
                              void* d_out, int out_size, void* d_ws, size_t ws_size,
                              hipStream_t stream) {
    const float* pp   = (const float*)d_in[0];   // positive_prob [B]
    const float* pred = (const float*)d_in[1];   // predictions  [B, C]
    const int*   tgt  = (const int*)d_in[2];     // target       [B]
    float* out     = (float*)d_out;
    float* partial = (float*)d_ws;               // NBLK floats = 4 KB scratch

    loss_partial_kernel<<<NBLK, NTHR, 0, stream>>>(pp, pred, tgt, partial);
    loss_final_kernel<<<1, NTHR, 0, stream>>>(partial, out);
}

// Round 2
// 27.601 us; speedup vs baseline: 1.0017x; 1.0017x over previous
//
#include <hip/hip_runtime.h>
#include <math.h>

// CustomCombinedLoss: weighted-sum BCE over positive_prob + MultiMarginLoss(p=1, margin=0.5).
// B=16384 rows, C=2048 classes, f32. Pure streaming reduction over 134.2 MB -> HBM-bound.
// hinge identity: sum_{j!=y} max(0, m - x[y] + x[j]) = sum_all_j max(0, c + x[j]) - 0.5, c = 0.5 - x[y].

#define BN   16384
#define CN   2048
#define NBLK 2048
#define NTHR 256
#define RPB  (BN / NBLK)   // 8 contiguous rows per block

__global__ __launch_bounds__(NTHR) void loss_partial_kernel(
    const float* __restrict__ pp,     // [B] positive_prob
    const float* __restrict__ pred,   // [B*C] predictions
    const int*   __restrict__ tgt,    // [B] target in [0, C]
    float* __restrict__ partial)      // [NBLK] per-block partial sums
{
    const int tid  = threadIdx.x;
    const int row0 = blockIdx.x * RPB;

    float acc_h = 0.f;   // hinge terms (scaled by 1/C at the end)
    float acc_o = 0.f;   // BCE terms + per-row corrections

    #pragma unroll
    for (int r = 0; r < RPB; ++r) {
        const int row = row0 + r;
        const float* rowp = pred + (size_t)row * CN;
        const float4* rp4 = (const float4*)rowp;

        // issue row loads unconditionally — no dependence on tgt
        const float4 a = rp4[tid];
        const float4 b = rp4[tid + NTHR];

        const int   t = tgt[row];
        const float m = (t != 0) ? 1.0f : 0.0f;
        const int   y = (t > 0) ? (t - 1) : 0;
        const float xy = rowp[y];            // uniform per block -> broadcast
        const float c  = 0.5f - xy;          // margin - x[y]

        float h = fmaxf(0.f, c + a.x) + fmaxf(0.f, c + a.y)
                + fmaxf(0.f, c + a.z) + fmaxf(0.f, c + a.w)
                + fmaxf(0.f, c + b.x) + fmaxf(0.f, c + b.y)
                + fmaxf(0.f, c + b.z) + fmaxf(0.f, c + b.w);
        acc_h += m * h;

        if (tid == 0) {
            // remove the j==y hinge term: max(0, margin) = 0.5 (only when t != 0)
            acc_h -= m * 0.5f;
            // BCE: positive (t!=0): -max(log p, -100); negative: -2*max(log1p(-p), -100)
            const float p = pp[row];
            const float lp  = fmaxf(logf(p),    -100.f);
            const float l1p = fmaxf(log1pf(-p), -100.f);
            acc_o -= (t != 0) ? lp : 2.0f * l1p;
        }
    }

    float acc = acc_h * (1.0f / CN) + acc_o;

    // deterministic block reduce: wave64 shuffle tree, then LDS across 4 waves
    #pragma unroll
    for (int off = 32; off > 0; off >>= 1)
        acc += __shfl_down(acc, off, 64);
    __shared__ float sm[NTHR / 64];
    if ((tid & 63) == 0) sm[tid >> 6] = acc;
    __syncthreads();
    if (tid == 0) {
        float s = 0.f;
        #pragma unroll
        for (int i = 0; i < NTHR / 64; ++i) s += sm[i];
        partial[blockIdx.x] = s;
    }
}

__global__ __launch_bounds__(NTHR) void loss_final_kernel(
    const float* __restrict__ partial, float* __restrict__ out)
{
    const int tid = threadIdx.x;
    // 2048 partials = 512 float4; 256 threads -> 2 float4 each
    const float4* p4 = (const float4*)partial;
    const float4 a = p4[tid];
    const float4 b = p4[tid + NTHR];
    float acc = (a.x + a.y) + (a.z + a.w) + (b.x + b.y) + (b.z + b.w);
    #pragma unroll
    for (int off = 32; off > 0; off >>= 1)
        acc += __shfl_down(acc, off, 64);
    __shared__ float sm[NTHR / 64];
    if ((tid & 63) == 0) sm[tid >> 6] = acc;
    __syncthreads();
    if (tid == 0) {
        float s = 0.f;
        #pragma unroll
        for (int i = 0; i < NTHR / 64; ++i) s += sm[i];
        out[0] = s;
    }
}

extern "C" void kernel_launch(void* const* d_in, const int* in_sizes, int n_in,
                              void* d_out, int out_size, void* d_ws, size_t ws_size,
                              hipStream_t stream) {
    const float* pp   = (const float*)d_in[0];   // positive_prob [B]
    const float* pred = (const float*)d_in[1];   // predictions  [B, C]
    const int*   tgt  = (const int*)d_in[2];     // target       [B]
    float* out     = (float*)d_out;
    float* partial = (float*)d_ws;               // NBLK floats = 8 KB scratch

    loss_partial_kernel<<<NBLK, NTHR, 0, stream>>>(pp, pred, tgt, partial);
    loss_final_kernel<<<1, NTHR, 0, stream>>>(partial, out);
}